// Round 4
// baseline (426.116 us; speedup 1.0000x reference)
//
#include <hip/hip_runtime.h>

#define DIM 128        // DIN == DOUT
#define D10 12         // DIM/10

// bucket partition parameters
#define RPB 512        // rows per bucket (rlow fits 9 bits)
#define NB_MAX 200     // max buckets supported by partition path (N <= 102400)
#define SCAP 96        // LDS slots per bucket per block (mean ~32, 10+ sigma headroom)
#define CAPG 12288     // global entries per bucket (max realistic ~8.8K)

typedef __attribute__((ext_vector_type(8))) short bf16x8;
typedef __attribute__((ext_vector_type(4))) float f32x4;

__device__ __forceinline__ void fma4(float4& a, float s, const float4& w) {
    a.x = fmaf(s, w.x, a.x);
    a.y = fmaf(s, w.y, a.y);
    a.z = fmaf(s, w.z, a.z);
    a.w = fmaf(s, w.w, a.w);
}

__device__ __forceinline__ unsigned short f2bf(float f) {
    union { float f; unsigned int u; } v; v.f = f;
    unsigned int u = v.u;
    unsigned int r = (u + 0x7FFFu + ((u >> 16) & 1u)) >> 16;   // RTNE
    return (unsigned short)r;
}

// ---------------- W transpose + bf16 cast: Wt[n][k] = bf16(W[k][n]) ----------------

__global__ void k_wt(const float* __restrict__ W, unsigned short* __restrict__ Wt) {
    int i = blockIdx.x * 256 + threadIdx.x;
    if (i >= DIM * DIM) return;
    int k = i >> 7, nn = i & 127;
    Wt[nn * DIM + k] = f2bf(W[i]);
}

// ---------------- fused MFMA GEMM: s12 = (x@W)[:, :12] raw; out[:, 12:] = prelu((x@W)[:, 12:] + bias) ----------------
// 256 thr = 4 waves, 64 rows/block. LDS: x 16KB + Wt 32KB, XOR-swizzled.

__global__ __launch_bounds__(256) void k_gemm(
    const float4* __restrict__ xv, float* __restrict__ out,
    const uint4* __restrict__ Wtv,            // bf16 Wt[n][k]
    const float* __restrict__ bias, const float* __restrict__ alpha,
    float* __restrict__ s12, int n)
{
    __shared__ alignas(16) char lds[48 * 1024];
    char* xs  = lds;            // 64 rows x 128 k x 2B = 16 KB
    char* wsm = lds + 16384;    // 128 n  x 128 k x 2B = 32 KB

    int tid = threadIdx.x;
    int rowbase = blockIdx.x * 64;

#pragma unroll
    for (int ii = 0; ii < 8; ++ii) {
        int i = tid + ii * 256;                  // 2048 x 16B
        int nn = i >> 4, kq = i & 15;
        uint4 v = Wtv[nn * 16 + kq];
        int byte = (nn * 256 + kq * 16) ^ ((nn & 7) << 4);
        *reinterpret_cast<uint4*>(wsm + byte) = v;
    }
#pragma unroll
    for (int ii = 0; ii < 8; ++ii) {
        int i = tid + ii * 256;                  // 2048 x float4
        int lr = i >> 5, c4 = i & 31;
        int r = rowbase + lr;
        float4 v; v.x = v.y = v.z = v.w = 0.f;
        if (r < n) v = xv[(size_t)r * 32 + c4];
        uint2 p;
        p.x = (unsigned int)f2bf(v.x) | ((unsigned int)f2bf(v.y) << 16);
        p.y = (unsigned int)f2bf(v.z) | ((unsigned int)f2bf(v.w) << 16);
        int byte = (lr * 256 + c4 * 8) ^ ((lr & 7) << 4);
        *reinterpret_cast<uint2*>(xs + byte) = p;
    }
    __syncthreads();

    int wv = tid >> 6;
    int lane = tid & 63;
    int lr0 = wv * 16;
    int arow = lr0 + (lane & 15);
    int kgrp = (lane >> 4) * 8;

    f32x4 acc[8];
#pragma unroll
    for (int t = 0; t < 8; ++t) acc[t] = (f32x4){0.f, 0.f, 0.f, 0.f};

#pragma unroll
    for (int kb = 0; kb < 4; ++kb) {
        int koff = kb * 32 + kgrp;
        int abyte = (arow * 256 + koff * 2) ^ ((arow & 7) << 4);
        bf16x8 a = *reinterpret_cast<const bf16x8*>(xs + abyte);
#pragma unroll
        for (int t = 0; t < 8; ++t) {
            int c = t * 16 + (lane & 15);
            int bbyte = (c * 256 + koff * 2) ^ ((c & 7) << 4);
            bf16x8 b = *reinterpret_cast<const bf16x8*>(wsm + bbyte);
            acc[t] = __builtin_amdgcn_mfma_f32_16x16x32_bf16(a, b, acc[t], 0, 0, 0);
        }
    }

    int colbase = lane & 15;
    int rgrp = (lane >> 4) * 4;
    float bi[8], al[8];
#pragma unroll
    for (int t = 0; t < 8; ++t) {
        int c = t * 16 + colbase;
        bi[t] = bias[c];
        al[t] = alpha[c];
    }
#pragma unroll
    for (int j = 0; j < 4; ++j) {
        int r = rowbase + lr0 + rgrp + j;
        if (r >= n) continue;
#pragma unroll
        for (int t = 0; t < 8; ++t) {
            int c = t * 16 + colbase;
            float h = acc[t][j];
            if (t == 0 && colbase < D10) {
                s12[(size_t)r * 12 + colbase] = h;    // raw; epilogue done in k_agg
            } else {
                h += bi[t];
                h = h >= 0.f ? h : al[t] * h;
                out[(size_t)r * DIM + c] = h;
            }
        }
    }
}

// ---------------- LDS-staged bucket partition ----------------
// entry = (rlow9 << 17) | col17 ; bucket b = row >> 9

__global__ __launch_bounds__(512) void k_partition(
    const int* __restrict__ row, const int* __restrict__ col, int E, int nb,
    int* __restrict__ gcur, int* __restrict__ ebuf,
    float* __restrict__ agg12, int* __restrict__ deg_g,
    const float* __restrict__ s12)
{
    __shared__ int s_cnt[NB_MAX];
    __shared__ int s_buf[NB_MAX * SCAP];   // 76.8 KB

    int tid = threadIdx.x;
    for (int i = tid; i < NB_MAX; i += 512) s_cnt[i] = 0;
    __syncthreads();

    int chunk = (E + gridDim.x - 1) / gridDim.x;
    int start = blockIdx.x * chunk;
    int end = start + chunk; if (end > E) end = E;

    for (int i = start + tid; i < end; i += 512) {
        int r = row[i], c = col[i];
        int b = r >> 9;
        int e = ((r & (RPB - 1)) << 17) | c;
        int p = atomicAdd(&s_cnt[b], 1);
        if (p < SCAP) {
            s_buf[b * SCAP + p] = e;
        } else {
            // rare LDS overflow: direct global append
            int q = atomicAdd(&gcur[b], 1);
            if (q < CAPG) {
                ebuf[(size_t)b * CAPG + q] = e;
            } else {
                // capacity overflow: atomic fallback into agg12
                atomicAdd(&deg_g[r], 1);
#pragma unroll
                for (int j = 0; j < 12; ++j)
                    atomicAdd(&agg12[(size_t)r * 12 + j], s12[(size_t)c * 12 + j]);
            }
        }
    }
    __syncthreads();

    // cooperative flush: wave w handles buckets w, w+8, ...
    int wv = tid >> 6, ln = tid & 63;
    for (int b = wv; b < nb; b += 8) {
        int cnt = s_cnt[b]; if (cnt > SCAP) cnt = SCAP;
        if (cnt == 0) continue;
        int base = 0;
        if (ln == 0) base = atomicAdd(&gcur[b], cnt);
        base = __shfl(base, 0, 64);
        for (int j = ln; j < cnt; j += 64) {
            int e = s_buf[b * SCAP + j];
            int q = base + j;
            if (q < CAPG) {
                ebuf[(size_t)b * CAPG + q] = e;
            } else {
                int r = b * RPB + (e >> 17);
                int c = e & 0x1FFFF;
                atomicAdd(&deg_g[r], 1);
#pragma unroll
                for (int jj = 0; jj < 12; ++jj)
                    atomicAdd(&agg12[(size_t)r * 12 + jj], s12[(size_t)c * 12 + jj]);
            }
        }
    }
}

// ---------------- bucket aggregation + fused epilogue for cols 0..11 ----------------

__global__ __launch_bounds__(1024) void k_agg(
    const float4* __restrict__ s12v, const int* __restrict__ gcur,
    const int* __restrict__ ebuf, const float* __restrict__ agg12,
    const int* __restrict__ deg_g,
    const float* __restrict__ bias, const float* __restrict__ alpha,
    float* __restrict__ out, int n)
{
    __shared__ float sacc[RPB * 12];   // 24 KB
    __shared__ int   sdeg[RPB];        // 2 KB

    int b = blockIdx.x;
    int tid = threadIdx.x;
    for (int i = tid; i < RPB * 12; i += 1024) sacc[i] = 0.f;
    for (int i = tid; i < RPB; i += 1024) sdeg[i] = 0;
    __syncthreads();

    int size = gcur[b]; if (size > CAPG) size = CAPG;
    const int* eb = ebuf + (size_t)b * CAPG;

    int team = tid >> 2, ln = tid & 3;   // 256 teams of 4
    for (int i = team; i < size; i += 256) {
        int e = eb[i];
        int rl = e >> 17;
        int c  = e & 0x1FFFF;
        if (ln < 3) {
            float4 v = s12v[(size_t)c * 3 + ln];
            atomicAdd(&sacc[rl * 12 + ln * 4 + 0], v.x);
            atomicAdd(&sacc[rl * 12 + ln * 4 + 1], v.y);
            atomicAdd(&sacc[rl * 12 + ln * 4 + 2], v.z);
            atomicAdd(&sacc[rl * 12 + ln * 4 + 3], v.w);
        } else {
            atomicAdd(&sdeg[rl], 1);
        }
    }
    __syncthreads();

    int rowbase = b * RPB;
    for (int i = tid; i < RPB * 12; i += 1024) {
        int rl = i / 12, c = i - rl * 12;
        int r = rowbase + rl;
        if (r >= n) continue;
        int d = sdeg[rl] + deg_g[r];
        float a = (sacc[i] + agg12[(size_t)r * 12 + c]) / (float)(d > 0 ? d : 1);
        float h = a + bias[c];
        h = h >= 0.f ? h : alpha[c] * h;
        out[(size_t)r * DIM + c] = h;
    }
}

// ---------------- tier C helpers (atomic fallback path) ----------------

__global__ void k_count_deg(const int* __restrict__ row, int E, int* __restrict__ deg) {
    int i = blockIdx.x * blockDim.x + threadIdx.x;
    int stride = gridDim.x * blockDim.x;
    for (; i < E; i += stride) atomicAdd(&deg[row[i]], 1);
}

__global__ __launch_bounds__(256) void k_s12(const float4* __restrict__ xv,
                                             const float4* __restrict__ Wv,
                                             float4* __restrict__ s12v, int n) {
    __shared__ float4 xs[64 * 33];
    __shared__ float4 w12[128 * 3];

    int tid = threadIdx.x;
    int rowbase = blockIdx.x * 64;

    for (int i = tid; i < 128 * 3; i += 256) {
        int k = i / 3, q = i - k * 3;
        w12[i] = Wv[k * 32 + q];
    }
    for (int i = tid; i < 64 * 32; i += 256) {
        int r = rowbase + (i >> 5);
        float4 v; v.x = v.y = v.z = v.w = 0.f;
        if (r < n) v = xv[(size_t)r * 32 + (i & 31)];
        xs[(i >> 5) * 33 + (i & 31)] = v;
    }
    __syncthreads();

    if (tid < 192) {
        int lrow = tid / 3;
        int q = tid - lrow * 3;
        const float4* xr = &xs[lrow * 33];
        float4 acc; acc.x = acc.y = acc.z = acc.w = 0.f;
#pragma unroll 4
        for (int k4 = 0; k4 < 32; ++k4) {
            float4 v = xr[k4];
            float4 w0 = w12[(k4 * 4 + 0) * 3 + q];
            float4 w1 = w12[(k4 * 4 + 1) * 3 + q];
            float4 w2 = w12[(k4 * 4 + 2) * 3 + q];
            float4 w3 = w12[(k4 * 4 + 3) * 3 + q];
            fma4(acc, v.x, w0); fma4(acc, v.y, w1);
            fma4(acc, v.z, w2); fma4(acc, v.w, w3);
        }
        int grow = rowbase + lrow;
        if (grow < n) s12v[(size_t)grow * 3 + q] = acc;
    }
}

__global__ void k_edge_atomic12(const float* __restrict__ s12, const int* __restrict__ row,
                                const int* __restrict__ col, int E, float* __restrict__ agg) {
    int i = blockIdx.x * blockDim.x + threadIdx.x;
    int stride = gridDim.x * blockDim.x;
    long long total = (long long)E * 16;
    for (long long g = i; g < total; g += stride) {
        int e = (int)(g >> 4), l = (int)(g & 15);
        if (l < 12) {
            atomicAdd(&agg[(size_t)row[e] * 12 + l], s12[(size_t)col[e] * 12 + l]);
        }
    }
}

// tier C final: full epilogue incl. agg/deg for cols 0..11
__global__ __launch_bounds__(256) void k_final_mfma(
    const float4* __restrict__ xv, float* __restrict__ out,
    const uint4* __restrict__ Wtv,
    const float* __restrict__ bias, const float* __restrict__ alpha,
    const float* __restrict__ agg, const int* __restrict__ deg, int n)
{
    __shared__ alignas(16) char lds[48 * 1024];
    char* xs  = lds;
    char* wsm = lds + 16384;

    int tid = threadIdx.x;
    int rowbase = blockIdx.x * 64;

#pragma unroll
    for (int ii = 0; ii < 8; ++ii) {
        int i = tid + ii * 256;
        int nn = i >> 4, kq = i & 15;
        uint4 v = Wtv[nn * 16 + kq];
        int byte = (nn * 256 + kq * 16) ^ ((nn & 7) << 4);
        *reinterpret_cast<uint4*>(wsm + byte) = v;
    }
#pragma unroll
    for (int ii = 0; ii < 8; ++ii) {
        int i = tid + ii * 256;
        int lr = i >> 5, c4 = i & 31;
        int r = rowbase + lr;
        float4 v; v.x = v.y = v.z = v.w = 0.f;
        if (r < n) v = xv[(size_t)r * 32 + c4];
        uint2 p;
        p.x = (unsigned int)f2bf(v.x) | ((unsigned int)f2bf(v.y) << 16);
        p.y = (unsigned int)f2bf(v.z) | ((unsigned int)f2bf(v.w) << 16);
        int byte = (lr * 256 + c4 * 8) ^ ((lr & 7) << 4);
        *reinterpret_cast<uint2*>(xs + byte) = p;
    }
    __syncthreads();

    int wv = tid >> 6;
    int lane = tid & 63;
    int lr0 = wv * 16;
    int arow = lr0 + (lane & 15);
    int kgrp = (lane >> 4) * 8;

    f32x4 acc[8];
#pragma unroll
    for (int t = 0; t < 8; ++t) acc[t] = (f32x4){0.f, 0.f, 0.f, 0.f};

#pragma unroll
    for (int kb = 0; kb < 4; ++kb) {
        int koff = kb * 32 + kgrp;
        int abyte = (arow * 256 + koff * 2) ^ ((arow & 7) << 4);
        bf16x8 a = *reinterpret_cast<const bf16x8*>(xs + abyte);
#pragma unroll
        for (int t = 0; t < 8; ++t) {
            int c = t * 16 + (lane & 15);
            int bbyte = (c * 256 + koff * 2) ^ ((c & 7) << 4);
            bf16x8 b = *reinterpret_cast<const bf16x8*>(wsm + bbyte);
            acc[t] = __builtin_amdgcn_mfma_f32_16x16x32_bf16(a, b, acc[t], 0, 0, 0);
        }
    }

    int colbase = lane & 15;
    int rgrp = (lane >> 4) * 4;
    float bi[8], al[8];
#pragma unroll
    for (int t = 0; t < 8; ++t) {
        int c = t * 16 + colbase;
        bi[t] = bias[c];
        al[t] = alpha[c];
    }
#pragma unroll
    for (int j = 0; j < 4; ++j) {
        int r = rowbase + lr0 + rgrp + j;
        if (r >= n) continue;
        float invd = 1.f;
        if (colbase < D10) {
            int d = deg[r];
            invd = 1.f / (float)(d > 0 ? d : 1);
        }
#pragma unroll
        for (int t = 0; t < 8; ++t) {
            int c = t * 16 + colbase;
            float h;
            if (t == 0 && colbase < D10) {
                h = agg[(size_t)r * 12 + c] * invd;
            } else {
                h = acc[t][j];
            }
            h += bi[t];
            h = h >= 0.f ? h : al[t] * h;
            out[(size_t)r * DIM + c] = h;
        }
    }
}

// ---------------- tier E legacy ----------------

__global__ void k_edge_atomic(const float4* __restrict__ xv, const int* __restrict__ row,
                              const int* __restrict__ col, int E, float* __restrict__ out) {
    int i = blockIdx.x * blockDim.x + threadIdx.x;
    int stride = gridDim.x * blockDim.x;
    int total = E * 32;
    for (; i < total; i += stride) {
        int e = i >> 5, lane = i & 31;
        int r = row[e], c = col[e];
        float4 v = xv[(size_t)c * 32 + lane];
        float* dst = out + (size_t)r * DIM + lane * 4;
        atomicAdd(dst + 0, v.x);
        atomicAdd(dst + 1, v.y);
        atomicAdd(dst + 2, v.z);
        atomicAdd(dst + 3, v.w);
    }
}

__global__ __launch_bounds__(256) void k_final_legacy(const float4* __restrict__ xv,
                                                      float4* __restrict__ outv,
                                                      const float4* __restrict__ Wv,
                                                      const float4* __restrict__ biasv,
                                                      const float4* __restrict__ alphav,
                                                      const int* __restrict__ deg, int n) {
    __shared__ float4 Ws4[DIM * 32];
    __shared__ float4 vs4[2][32 * 32];

    int tid = threadIdx.x;
    int rowbase = blockIdx.x * 32;
    if (rowbase >= n) return;

    for (int i = tid; i < DIM * 32; i += 256) Ws4[i] = Wv[i];
    for (int i = tid; i < 32 * 32; i += 256) {
        int r = rowbase + (i >> 5);
        if (r < n) {
            vs4[0][i] = outv[(size_t)r * 32 + (i & 31)];
            vs4[1][i] = xv[(size_t)r * 32 + (i & 31)];
        }
    }
    __syncthreads();

    int tx = tid & 31;
    int ty = tid >> 5;
    int r0 = ty * 4;
    const float4* V = (tx < (D10 / 4)) ? vs4[0] : vs4[1];

    float4 acc[4];
#pragma unroll
    for (int r = 0; r < 4; r++) { acc[r].x = acc[r].y = acc[r].z = acc[r].w = 0.f; }

#pragma unroll 8
    for (int k4 = 0; k4 < 32; k4++) {
        float4 w0 = Ws4[(k4 * 4 + 0) * 32 + tx];
        float4 w1 = Ws4[(k4 * 4 + 1) * 32 + tx];
        float4 w2 = Ws4[(k4 * 4 + 2) * 32 + tx];
        float4 w3 = Ws4[(k4 * 4 + 3) * 32 + tx];
#pragma unroll
        for (int r = 0; r < 4; r++) {
            float4 v = V[(r0 + r) * 32 + k4];
            fma4(acc[r], v.x, w0); fma4(acc[r], v.y, w1);
            fma4(acc[r], v.z, w2); fma4(acc[r], v.w, w3);
        }
    }

    float4 b4 = biasv[tx];
    float4 a4 = alphav[tx];
#pragma unroll
    for (int r = 0; r < 4; r++) {
        int row = rowbase + r0 + r;
        if (row >= n) continue;
        float4 h = acc[r];
        if (tx < (D10 / 4)) {
            int d = deg[row];
            float invd = 1.0f / (float)(d > 0 ? d : 1);
            h.x *= invd; h.y *= invd; h.z *= invd; h.w *= invd;
        }
        h.x += b4.x; h.y += b4.y; h.z += b4.z; h.w += b4.w;
        h.x = h.x >= 0.f ? h.x : a4.x * h.x;
        h.y = h.y >= 0.f ? h.y : a4.y * h.y;
        h.z = h.z >= 0.f ? h.z : a4.z * h.z;
        h.w = h.w >= 0.f ? h.w : a4.w * h.w;
        outv[(size_t)row * 32 + tx] = h;
    }
}

// ---------------- launcher ----------------

extern "C" void kernel_launch(void* const* d_in, const int* in_sizes, int n_in,
                              void* d_out, int out_size, void* d_ws, size_t ws_size,
                              hipStream_t stream) {
    const float* x     = (const float*)d_in[0];
    const float* W     = (const float*)d_in[1];
    const float* bias  = (const float*)d_in[2];
    const float* alpha = (const float*)d_in[3];
    const int*   ei    = (const int*)d_in[4];

    int N = in_sizes[0] / DIM;
    int E = in_sizes[4] / 2;
    const int* row = ei;
    const int* col = ei + E;
    float* out = (float*)d_out;

    int gemm_blocks = (N + 63) / 64;
    int nb = (N + RPB - 1) / RPB;
    size_t wt_bytes = (size_t)DIM * DIM * 2;   // 32 KB

    // Tier A: Wt | s12[12N] | agg12[12N] | deg_g[N] | gcur[NB_MAX] | ebuf[nb*CAPG]
    size_t need_A = wt_bytes + ((size_t)(12 + 12 + 1) * N + NB_MAX) * 4
                  + (size_t)nb * CAPG * 4;
    // Tier C: Wt | s12 | agg12 | deg
    size_t need_C = wt_bytes + (size_t)(12 + 12 + 1) * N * 4;
    size_t need_E = (size_t)N * 4;

    if (nb <= NB_MAX && ws_size >= need_A) {
        unsigned short* Wt = (unsigned short*)d_ws;
        float* s12   = (float*)((char*)d_ws + wt_bytes);
        float* agg12 = s12 + (size_t)12 * N;
        int*   deg_g = (int*)(agg12 + (size_t)12 * N);
        int*   gcur  = deg_g + N;
        int*   ebuf  = gcur + NB_MAX;

        // zero agg12 + deg_g + gcur in one shot (contiguous)
        hipMemsetAsync(agg12, 0, ((size_t)13 * N + NB_MAX) * sizeof(float), stream);
        k_wt<<<(DIM * DIM + 255) / 256, 256, 0, stream>>>(W, Wt);
        k_gemm<<<gemm_blocks, 256, 0, stream>>>((const float4*)x, out, (const uint4*)Wt,
                                                bias, alpha, s12, N);
        k_partition<<<256, 512, 0, stream>>>(row, col, E, nb, gcur, ebuf,
                                             agg12, deg_g, s12);
        k_agg<<<nb, 1024, 0, stream>>>((const float4*)s12, gcur, ebuf, agg12, deg_g,
                                       bias, alpha, out, N);
    } else if (ws_size >= need_C) {
        unsigned short* Wt = (unsigned short*)d_ws;
        float* s12   = (float*)((char*)d_ws + wt_bytes);
        float* agg12 = s12 + (size_t)12 * N;
        int*   deg   = (int*)(agg12 + (size_t)12 * N);

        hipMemsetAsync(deg, 0, (size_t)N * sizeof(int), stream);
        hipMemsetAsync(agg12, 0, (size_t)12 * N * sizeof(float), stream);
        k_wt<<<(DIM * DIM + 255) / 256, 256, 0, stream>>>(W, Wt);
        k_s12<<<gemm_blocks, 256, 0, stream>>>((const float4*)x, (const float4*)W,
                                               (float4*)s12, N);
        k_count_deg<<<2048, 256, 0, stream>>>(row, E, deg);
        k_edge_atomic12<<<4096, 256, 0, stream>>>(s12, row, col, E, agg12);
        k_final_mfma<<<gemm_blocks, 256, 0, stream>>>((const float4*)x, out,
                                                      (const uint4*)Wt, bias, alpha,
                                                      agg12, deg, N);
    } else if (ws_size >= need_E) {
        int* deg = (int*)d_ws;
        hipMemsetAsync(out, 0, (size_t)N * DIM * sizeof(float), stream);
        hipMemsetAsync(deg, 0, (size_t)N * sizeof(int), stream);
        k_count_deg<<<2048, 256, 0, stream>>>(row, E, deg);
        k_edge_atomic<<<4096, 256, 0, stream>>>((const float4*)x, row, col, E, out);
        k_final_legacy<<<(N + 31) / 32, 256, 0, stream>>>((const float4*)x, (float4*)out,
                                                          (const float4*)W, (const float4*)bias,
                                                          (const float4*)alpha, deg, N);
    }
}

// Round 5
// 219.954 us; speedup vs baseline: 1.9373x; 1.9373x over previous
//
#include <hip/hip_runtime.h>

#define DIM 128        // DIN == DOUT
#define D10 12         // DIM/10

typedef __attribute__((ext_vector_type(8))) short bf16x8;
typedef __attribute__((ext_vector_type(4))) float f32x4;

__device__ __forceinline__ void fma4(float4& a, float s, const float4& w) {
    a.x = fmaf(s, w.x, a.x);
    a.y = fmaf(s, w.y, a.y);
    a.z = fmaf(s, w.z, a.z);
    a.w = fmaf(s, w.w, a.w);
}

__device__ __forceinline__ unsigned short f2bf(float f) {
    union { float f; unsigned int u; } v; v.f = f;
    unsigned int u = v.u;
    unsigned int r = (u + 0x7FFFu + ((u >> 16) & 1u)) >> 16;   // RTNE
    return (unsigned short)r;
}

// ---------------- W transpose + bf16 cast: Wt[n][k] = bf16(W[k][n]) ----------------

__global__ void k_wt(const float* __restrict__ W, unsigned short* __restrict__ Wt) {
    int i = blockIdx.x * 256 + threadIdx.x;
    if (i >= DIM * DIM) return;
    int k = i >> 7, nn = i & 127;
    Wt[nn * DIM + k] = f2bf(W[i]);
}

// ---------------- fused MFMA GEMM ----------------
// s12 = (x@W)[:, :12] raw; out[:, 12:] = prelu((x@W)[:, 12:] + bias)
// 256 thr = 4 waves, 64 rows/block. LDS: x 16KB + Wt 32KB, XOR-swizzled.

__global__ __launch_bounds__(256) void k_gemm(
    const float4* __restrict__ xv, float* __restrict__ out,
    const uint4* __restrict__ Wtv,            // bf16 Wt[n][k]
    const float* __restrict__ bias, const float* __restrict__ alpha,
    float* __restrict__ s12, int n)
{
    __shared__ alignas(16) char lds[48 * 1024];
    char* xs  = lds;            // 64 rows x 128 k x 2B = 16 KB
    char* wsm = lds + 16384;    // 128 n  x 128 k x 2B = 32 KB

    int tid = threadIdx.x;
    int rowbase = blockIdx.x * 64;

#pragma unroll
    for (int ii = 0; ii < 8; ++ii) {
        int i = tid + ii * 256;                  // 2048 x 16B
        int nn = i >> 4, kq = i & 15;
        uint4 v = Wtv[nn * 16 + kq];
        int byte = (nn * 256 + kq * 16) ^ ((nn & 7) << 4);
        *reinterpret_cast<uint4*>(wsm + byte) = v;
    }
#pragma unroll
    for (int ii = 0; ii < 8; ++ii) {
        int i = tid + ii * 256;                  // 2048 x float4
        int lr = i >> 5, c4 = i & 31;
        int r = rowbase + lr;
        float4 v; v.x = v.y = v.z = v.w = 0.f;
        if (r < n) v = xv[(size_t)r * 32 + c4];
        uint2 p;
        p.x = (unsigned int)f2bf(v.x) | ((unsigned int)f2bf(v.y) << 16);
        p.y = (unsigned int)f2bf(v.z) | ((unsigned int)f2bf(v.w) << 16);
        int byte = (lr * 256 + c4 * 8) ^ ((lr & 7) << 4);
        *reinterpret_cast<uint2*>(xs + byte) = p;
    }
    __syncthreads();

    int wv = tid >> 6;
    int lane = tid & 63;
    int lr0 = wv * 16;
    int arow = lr0 + (lane & 15);
    int kgrp = (lane >> 4) * 8;

    f32x4 acc[8];
#pragma unroll
    for (int t = 0; t < 8; ++t) acc[t] = (f32x4){0.f, 0.f, 0.f, 0.f};

#pragma unroll
    for (int kb = 0; kb < 4; ++kb) {
        int koff = kb * 32 + kgrp;
        int abyte = (arow * 256 + koff * 2) ^ ((arow & 7) << 4);
        bf16x8 a = *reinterpret_cast<const bf16x8*>(xs + abyte);
#pragma unroll
        for (int t = 0; t < 8; ++t) {
            int c = t * 16 + (lane & 15);
            int bbyte = (c * 256 + koff * 2) ^ ((c & 7) << 4);
            bf16x8 b = *reinterpret_cast<const bf16x8*>(wsm + bbyte);
            acc[t] = __builtin_amdgcn_mfma_f32_16x16x32_bf16(a, b, acc[t], 0, 0, 0);
        }
    }

    int colbase = lane & 15;
    int rgrp = (lane >> 4) * 4;
    float bi[8], al[8];
#pragma unroll
    for (int t = 0; t < 8; ++t) {
        int c = t * 16 + colbase;
        bi[t] = bias[c];
        al[t] = alpha[c];
    }
#pragma unroll
    for (int j = 0; j < 4; ++j) {
        int r = rowbase + lr0 + rgrp + j;
        if (r >= n) continue;
#pragma unroll
        for (int t = 0; t < 8; ++t) {
            int c = t * 16 + colbase;
            float h = acc[t][j];
            if (t == 0 && colbase < D10) {
                s12[(size_t)r * 12 + colbase] = h;    // raw; epilogue in k_epi12
            } else {
                h += bi[t];
                h = h >= 0.f ? h : al[t] * h;
                out[(size_t)r * DIM + c] = h;
            }
        }
    }
}

// ---------------- edge aggregation: direct memory-side fp32 atomics ----------------
// 16 lanes per edge: lanes 0..11 add s12[col] into agg12[row]; lane 12 counts deg.

__global__ void k_edge_agg(const float* __restrict__ s12,
                           const int* __restrict__ row, const int* __restrict__ col,
                           long long total, float* __restrict__ agg12,
                           int* __restrict__ deg) {
    long long i = (long long)blockIdx.x * blockDim.x + threadIdx.x;
    long long stride = (long long)gridDim.x * blockDim.x;
    for (long long g = i; g < total; g += stride) {
        int e = (int)(g >> 4), l = (int)(g & 15);
        int r = row[e];
        if (l < 12) {
            atomicAdd(&agg12[(size_t)r * 12 + l], s12[(size_t)col[e] * 12 + l]);
        } else if (l == 12) {
            atomicAdd(&deg[r], 1);
        }
    }
}

// ---------------- epilogue for cols 0..11: out = prelu(agg/deg + bias) ----------------

__global__ void k_epi12(const float4* __restrict__ aggv, const int* __restrict__ deg,
                        const float* __restrict__ bias, const float* __restrict__ alpha,
                        float* __restrict__ out, int n) {
    int gid = blockIdx.x * blockDim.x + threadIdx.x;
    if (gid >= n * 3) return;
    int r = gid / 3, q = gid - r * 3;
    float4 a = aggv[gid];
    int d = deg[r];
    float invd = 1.f / (float)(d > 0 ? d : 1);
    float4 h;
    h.x = a.x * invd + bias[q * 4 + 0];
    h.y = a.y * invd + bias[q * 4 + 1];
    h.z = a.z * invd + bias[q * 4 + 2];
    h.w = a.w * invd + bias[q * 4 + 3];
    h.x = h.x >= 0.f ? h.x : alpha[q * 4 + 0] * h.x;
    h.y = h.y >= 0.f ? h.y : alpha[q * 4 + 1] * h.y;
    h.z = h.z >= 0.f ? h.z : alpha[q * 4 + 2] * h.z;
    h.w = h.w >= 0.f ? h.w : alpha[q * 4 + 3] * h.w;
    *reinterpret_cast<float4*>(out + (size_t)r * DIM + q * 4) = h;
}

// ---------------- tier E legacy (tiny workspace fallback) ----------------

__global__ void k_count_deg(const int* __restrict__ row, int E, int* __restrict__ deg) {
    int i = blockIdx.x * blockDim.x + threadIdx.x;
    int stride = gridDim.x * blockDim.x;
    for (; i < E; i += stride) atomicAdd(&deg[row[i]], 1);
}

__global__ void k_edge_atomic(const float4* __restrict__ xv, const int* __restrict__ row,
                              const int* __restrict__ col, int E, float* __restrict__ out) {
    int i = blockIdx.x * blockDim.x + threadIdx.x;
    int stride = gridDim.x * blockDim.x;
    int total = E * 32;
    for (; i < total; i += stride) {
        int e = i >> 5, lane = i & 31;
        int r = row[e], c = col[e];
        float4 v = xv[(size_t)c * 32 + lane];
        float* dst = out + (size_t)r * DIM + lane * 4;
        atomicAdd(dst + 0, v.x);
        atomicAdd(dst + 1, v.y);
        atomicAdd(dst + 2, v.z);
        atomicAdd(dst + 3, v.w);
    }
}

__global__ __launch_bounds__(256) void k_final_legacy(const float4* __restrict__ xv,
                                                      float4* __restrict__ outv,
                                                      const float4* __restrict__ Wv,
                                                      const float4* __restrict__ biasv,
                                                      const float4* __restrict__ alphav,
                                                      const int* __restrict__ deg, int n) {
    __shared__ float4 Ws4[DIM * 32];
    __shared__ float4 vs4[2][32 * 32];

    int tid = threadIdx.x;
    int rowbase = blockIdx.x * 32;
    if (rowbase >= n) return;

    for (int i = tid; i < DIM * 32; i += 256) Ws4[i] = Wv[i];
    for (int i = tid; i < 32 * 32; i += 256) {
        int r = rowbase + (i >> 5);
        if (r < n) {
            vs4[0][i] = outv[(size_t)r * 32 + (i & 31)];
            vs4[1][i] = xv[(size_t)r * 32 + (i & 31)];
        }
    }
    __syncthreads();

    int tx = tid & 31;
    int ty = tid >> 5;
    int r0 = ty * 4;
    const float4* V = (tx < (D10 / 4)) ? vs4[0] : vs4[1];

    float4 acc[4];
#pragma unroll
    for (int r = 0; r < 4; r++) { acc[r].x = acc[r].y = acc[r].z = acc[r].w = 0.f; }

#pragma unroll 8
    for (int k4 = 0; k4 < 32; k4++) {
        float4 w0 = Ws4[(k4 * 4 + 0) * 32 + tx];
        float4 w1 = Ws4[(k4 * 4 + 1) * 32 + tx];
        float4 w2 = Ws4[(k4 * 4 + 2) * 32 + tx];
        float4 w3 = Ws4[(k4 * 4 + 3) * 32 + tx];
#pragma unroll
        for (int r = 0; r < 4; r++) {
            float4 v = V[(r0 + r) * 32 + k4];
            fma4(acc[r], v.x, w0); fma4(acc[r], v.y, w1);
            fma4(acc[r], v.z, w2); fma4(acc[r], v.w, w3);
        }
    }

    float4 b4 = biasv[tx];
    float4 a4 = alphav[tx];
#pragma unroll
    for (int r = 0; r < 4; r++) {
        int row = rowbase + r0 + r;
        if (row >= n) continue;
        float4 h = acc[r];
        if (tx < (D10 / 4)) {
            int d = deg[row];
            float invd = 1.0f / (float)(d > 0 ? d : 1);
            h.x *= invd; h.y *= invd; h.z *= invd; h.w *= invd;
        }
        h.x += b4.x; h.y += b4.y; h.z += b4.z; h.w += b4.w;
        h.x = h.x >= 0.f ? h.x : a4.x * h.x;
        h.y = h.y >= 0.f ? h.y : a4.y * h.y;
        h.z = h.z >= 0.f ? h.z : a4.z * h.z;
        h.w = h.w >= 0.f ? h.w : a4.w * h.w;
        outv[(size_t)row * 32 + tx] = h;
    }
}

// ---------------- launcher ----------------

extern "C" void kernel_launch(void* const* d_in, const int* in_sizes, int n_in,
                              void* d_out, int out_size, void* d_ws, size_t ws_size,
                              hipStream_t stream) {
    const float* x     = (const float*)d_in[0];
    const float* W     = (const float*)d_in[1];
    const float* bias  = (const float*)d_in[2];
    const float* alpha = (const float*)d_in[3];
    const int*   ei    = (const int*)d_in[4];

    int N = in_sizes[0] / DIM;
    int E = in_sizes[4] / 2;
    const int* row = ei;
    const int* col = ei + E;
    float* out = (float*)d_out;

    int gemm_blocks = (N + 63) / 64;
    size_t wt_bytes = (size_t)DIM * DIM * 2;   // 32 KB, 16B-aligned

    // Tier A: Wt | s12[12N] | agg12[12N] | deg[N]
    size_t need_A = wt_bytes + (size_t)(12 + 12 + 1) * N * 4;
    size_t need_E = (size_t)N * 4;

    if (ws_size >= need_A) {
        unsigned short* Wt = (unsigned short*)d_ws;
        float* s12   = (float*)((char*)d_ws + wt_bytes);
        float* agg12 = s12 + (size_t)12 * N;
        int*   deg   = (int*)(agg12 + (size_t)12 * N);

        // zero agg12 + deg in one shot (contiguous, 13N words)
        hipMemsetAsync(agg12, 0, (size_t)13 * N * sizeof(float), stream);
        k_wt<<<(DIM * DIM + 255) / 256, 256, 0, stream>>>(W, Wt);
        k_gemm<<<gemm_blocks, 256, 0, stream>>>((const float4*)x, out, (const uint4*)Wt,
                                                bias, alpha, s12, N);
        long long total = (long long)E * 16;
        k_edge_agg<<<4096, 256, 0, stream>>>(s12, row, col, total, agg12, deg);
        k_epi12<<<(3 * N + 255) / 256, 256, 0, stream>>>((const float4*)agg12, deg,
                                                         bias, alpha, out, N);
    } else if (ws_size >= need_E) {
        int* deg = (int*)d_ws;
        hipMemsetAsync(out, 0, (size_t)N * DIM * sizeof(float), stream);
        hipMemsetAsync(deg, 0, (size_t)N * sizeof(int), stream);
        k_count_deg<<<2048, 256, 0, stream>>>(row, E, deg);
        k_edge_atomic<<<4096, 256, 0, stream>>>((const float4*)x, row, col, E, out);
        k_final_legacy<<<(N + 31) / 32, 256, 0, stream>>>((const float4*)x, (float4*)out,
                                                          (const float4*)W, (const float4*)bias,
                                                          (const float4*)alpha, deg, N);
    }
}